// Round 1
// baseline (774.237 us; speedup 1.0000x reference)
//
#include <hip/hip_runtime.h>
#include <stdint.h>

#define NN 50000
#define NE 800000
// D = 128 (hard-coded)

// ---------------- int64-vs-int32 edge_index autodetect ----------------
// If edge_index arrived as int64, the int32 view is [lo0,hi0,lo1,hi1,...]
// with hi==0 always (values < 50000). 16 consecutive zero high-words is
// conclusive (P ~ (1/50000)^16 for int32 false positive).
__global__ void k_detect(const int* __restrict__ ei, int* __restrict__ flag) {
    if (threadIdx.x == 0 && blockIdx.x == 0) {
        int z = 0;
        for (int i = 0; i < 16; i++) z += (ei[2 * i + 1] == 0) ? 1 : 0;
        *flag = (z == 16) ? 1 : 0;
    }
}

__global__ void k_count(const int* __restrict__ ei, const int* __restrict__ flag,
                        int* __restrict__ deg) {
    int e = blockIdx.x * 256 + threadIdx.x;
    if (e >= NE) return;
    int is64 = *flag;
    int d = is64 ? ei[2 * NE + 2 * e] : ei[NE + e];
    atomicAdd(&deg[d], 1);
}

// Single-block exclusive scan over 50000 degrees -> row_ptr, cursor, 1/max(deg,1)
__global__ __launch_bounds__(1024) void k_scan(const int* __restrict__ deg,
                                               int* __restrict__ row_ptr,
                                               int* __restrict__ cursor,
                                               float* __restrict__ rinv) {
    __shared__ int sp[1024];
    const int T = 1024;
    const int CH = (NN + T - 1) / T;  // 49
    int tid = threadIdx.x;
    int s = tid * CH;
    int local = 0;
    for (int c = 0; c < CH; c++) {
        int i = s + c;
        if (i < NN) local += deg[i];
    }
    sp[tid] = local;
    __syncthreads();
    for (int off = 1; off < T; off <<= 1) {
        int v = sp[tid];
        int add = (tid >= off) ? sp[tid - off] : 0;
        __syncthreads();
        sp[tid] = v + add;
        __syncthreads();
    }
    int run = (tid == 0) ? 0 : sp[tid - 1];
    for (int c = 0; c < CH; c++) {
        int i = s + c;
        if (i < NN) {
            int dgi = deg[i];
            row_ptr[i] = run;
            cursor[i] = run;
            rinv[i] = 1.0f / (float)max(dgi, 1);
            run += dgi;
        }
    }
    if (tid == T - 1) row_ptr[NN] = run;
}

__global__ void k_fill(const int* __restrict__ ei, const int* __restrict__ flag,
                       int* __restrict__ cursor, int* __restrict__ col) {
    int e = blockIdx.x * 256 + threadIdx.x;
    if (e >= NE) return;
    int is64 = *flag;
    int sv = is64 ? ei[2 * e] : ei[e];
    int dv = is64 ? ei[2 * NE + 2 * e] : ei[NE + e];
    int p = atomicAdd(&cursor[dv], 1);
    col[p] = sv;
}

// ---------------- mean aggregation: 32 lanes (float4) per node ----------------
__global__ __launch_bounds__(256) void k_aggregate(const float* __restrict__ h,
                                                   const int* __restrict__ row_ptr,
                                                   const int* __restrict__ col,
                                                   const float* __restrict__ rinv,
                                                   float* __restrict__ mean) {
    int node = blockIdx.x * 8 + (threadIdx.x >> 5);
    if (node >= NN) return;
    int lane = threadIdx.x & 31;
    int beg = row_ptr[node], end = row_ptr[node + 1];
    const float4* hp = (const float4*)h;
    float4 acc = make_float4(0.f, 0.f, 0.f, 0.f);
    int e = beg;
    // 2-deep manual unroll so two gathers are in flight
    for (; e + 1 < end; e += 2) {
        int s0 = col[e], s1 = col[e + 1];
        float4 v0 = hp[(size_t)s0 * 32 + lane];
        float4 v1 = hp[(size_t)s1 * 32 + lane];
        acc.x += v0.x; acc.y += v0.y; acc.z += v0.z; acc.w += v0.w;
        acc.x += v1.x; acc.y += v1.y; acc.z += v1.z; acc.w += v1.w;
    }
    if (e < end) {
        int s0 = col[e];
        float4 v0 = hp[(size_t)s0 * 32 + lane];
        acc.x += v0.x; acc.y += v0.y; acc.z += v0.z; acc.w += v0.w;
    }
    float r = rinv[node];
    acc.x *= r; acc.y *= r; acc.z *= r; acc.w *= r;
    ((float4*)mean)[(size_t)node * 32 + lane] = acc;
}

// ---------------- fused GEMM: out = mean@Wl^T + h@Wr^T + b (+ReLU) ----------------
// Block: 256 threads -> 128 nodes x 128 outs; per-thread 8x8 register tile.
// K = 256 (128 from mean/Wl, 128 from h/Wr) in chunks of 32 staged in LDS.
#define TM 128
#define TKc 32
#define LDA 132   // +4 pad: keeps 16B alignment for float4 LDS reads, breaks store conflicts
#define LDB 132

__global__ __launch_bounds__(256) void k_gemm(const float* __restrict__ Am,
                                              const float* __restrict__ Ah,
                                              const float* __restrict__ Wlp,
                                              const float* __restrict__ Wrp,
                                              const float* __restrict__ bias,
                                              float* __restrict__ outp, int relu) {
    __shared__ float As[TKc * LDA];
    __shared__ float Bs[TKc * LDB];
    const int t = threadIdx.x;
    const int nb0 = blockIdx.x * TM;
    const int n0 = (t >> 4) * 8;
    const int o0 = (t & 15) * 8;

    float acc[8][8];
#pragma unroll
    for (int i = 0; i < 8; i++)
#pragma unroll
        for (int j = 0; j < 8; j++) acc[i][j] = 0.f;

    for (int kc = 0; kc < 256; kc += TKc) {
        const float* Asrc = (kc < 128) ? Am : Ah;
        const float* Wsrc = (kc < 128) ? Wlp : Wrp;
        const int ks = kc & 127;
#pragma unroll
        for (int it = 0; it < 4; it++) {
            int lin = t + it * 256;   // 0..1023
            int row = lin >> 3;       // 0..127 (node for A, out for B)
            int kq = lin & 7;         // float4 index within 32-k chunk
            int kk = kq * 4;
            int gn = nb0 + row;
            float4 v = make_float4(0.f, 0.f, 0.f, 0.f);
            if (gn < NN) v = *(const float4*)(Asrc + (size_t)gn * 128 + ks + kk);
            As[(kk + 0) * LDA + row] = v.x;
            As[(kk + 1) * LDA + row] = v.y;
            As[(kk + 2) * LDA + row] = v.z;
            As[(kk + 3) * LDA + row] = v.w;
            float4 w = *(const float4*)(Wsrc + (size_t)row * 128 + ks + kk);
            Bs[(kk + 0) * LDB + row] = w.x;
            Bs[(kk + 1) * LDB + row] = w.y;
            Bs[(kk + 2) * LDB + row] = w.z;
            Bs[(kk + 3) * LDB + row] = w.w;
        }
        __syncthreads();
#pragma unroll 8
        for (int k = 0; k < TKc; k++) {
            float4 a0 = *(const float4*)&As[k * LDA + n0];
            float4 a1 = *(const float4*)&As[k * LDA + n0 + 4];
            float4 b0 = *(const float4*)&Bs[k * LDB + o0];
            float4 b1 = *(const float4*)&Bs[k * LDB + o0 + 4];
            float a[8] = {a0.x, a0.y, a0.z, a0.w, a1.x, a1.y, a1.z, a1.w};
            float b[8] = {b0.x, b0.y, b0.z, b0.w, b1.x, b1.y, b1.z, b1.w};
#pragma unroll
            for (int i = 0; i < 8; i++)
#pragma unroll
                for (int j = 0; j < 8; j++) acc[i][j] = fmaf(a[i], b[j], acc[i][j]);
        }
        __syncthreads();
    }

    float4 bv0 = *(const float4*)&bias[o0];
    float4 bv1 = *(const float4*)&bias[o0 + 4];
    float bb[8] = {bv0.x, bv0.y, bv0.z, bv0.w, bv1.x, bv1.y, bv1.z, bv1.w};
#pragma unroll
    for (int i = 0; i < 8; i++) {
        int gn = nb0 + n0 + i;
        if (gn < NN) {
            float4 r0, r1;
            r0.x = acc[i][0] + bb[0]; r0.y = acc[i][1] + bb[1];
            r0.z = acc[i][2] + bb[2]; r0.w = acc[i][3] + bb[3];
            r1.x = acc[i][4] + bb[4]; r1.y = acc[i][5] + bb[5];
            r1.z = acc[i][6] + bb[6]; r1.w = acc[i][7] + bb[7];
            if (relu) {
                r0.x = fmaxf(r0.x, 0.f); r0.y = fmaxf(r0.y, 0.f);
                r0.z = fmaxf(r0.z, 0.f); r0.w = fmaxf(r0.w, 0.f);
                r1.x = fmaxf(r1.x, 0.f); r1.y = fmaxf(r1.y, 0.f);
                r1.z = fmaxf(r1.z, 0.f); r1.w = fmaxf(r1.w, 0.f);
            }
            *(float4*)(outp + (size_t)gn * 128 + o0) = r0;
            *(float4*)(outp + (size_t)gn * 128 + o0 + 4) = r1;
        }
    }
}

extern "C" void kernel_launch(void* const* d_in, const int* in_sizes, int n_in,
                              void* d_out, int out_size, void* d_ws, size_t ws_size,
                              hipStream_t stream) {
    const float* x = (const float*)d_in[0];
    const int* ei = (const int*)d_in[1];
    const float* Wl[4] = {(const float*)d_in[2], (const float*)d_in[5],
                          (const float*)d_in[8], (const float*)d_in[11]};
    const float* bl[4] = {(const float*)d_in[3], (const float*)d_in[6],
                          (const float*)d_in[9], (const float*)d_in[12]};
    const float* Wr[4] = {(const float*)d_in[4], (const float*)d_in[7],
                          (const float*)d_in[10], (const float*)d_in[13]};
    float* out = (float*)d_out;

    char* p = (char*)d_ws;
    auto take = [&](size_t bytes) -> char* {
        char* r = p;
        p += (bytes + 255) & ~(size_t)255;
        return r;
    };
    int* flag = (int*)take(4);
    int* deg = (int*)take(NN * 4);
    int* row_ptr = (int*)take((NN + 1) * 4);
    int* cursor = (int*)take(NN * 4);
    float* rinv = (float*)take(NN * 4);
    int* col = (int*)take(NE * 4);
    float* bufA = (float*)take((size_t)NN * 128 * 4);
    float* bufB = (float*)take((size_t)NN * 128 * 4);
    float* mbuf = (float*)take((size_t)NN * 128 * 4);

    hipMemsetAsync(deg, 0, NN * 4, stream);
    k_detect<<<1, 64, 0, stream>>>(ei, flag);
    k_count<<<(NE + 255) / 256, 256, 0, stream>>>(ei, flag, deg);
    k_scan<<<1, 1024, 0, stream>>>(deg, row_ptr, cursor, rinv);
    k_fill<<<(NE + 255) / 256, 256, 0, stream>>>(ei, flag, cursor, col);

    const float* h = x;
    float* outs[4] = {bufA, bufB, bufA, out};
    for (int l = 0; l < 4; l++) {
        k_aggregate<<<(NN + 7) / 8, 256, 0, stream>>>(h, row_ptr, col, rinv, mbuf);
        k_gemm<<<(NN + TM - 1) / TM, 256, 0, stream>>>(mbuf, h, Wl[l], Wr[l], bl[l],
                                                       outs[l], l == 0 ? 1 : 0);
        h = outs[l];
    }
}

// Round 3
// 625.990 us; speedup vs baseline: 1.2368x; 1.2368x over previous
//
#include <hip/hip_runtime.h>
#include <stdint.h>

#define NN 50000
#define NE 800000
#define NB 196   // ceil(NN/256)
// D = 128 (hard-coded)

// ---------------- int64-vs-int32 edge_index autodetect ----------------
__global__ void k_detect(const int* __restrict__ ei, int* __restrict__ flag) {
    if (threadIdx.x == 0 && blockIdx.x == 0) {
        int z = 0;
        for (int i = 0; i < 16; i++) z += (ei[2 * i + 1] == 0) ? 1 : 0;
        *flag = (z == 16) ? 1 : 0;
    }
}

__global__ void k_count(const int* __restrict__ ei, const int* __restrict__ flag,
                        int* __restrict__ deg) {
    int e = blockIdx.x * 256 + threadIdx.x;
    if (e >= NE) return;
    int is64 = *flag;
    int d = is64 ? ei[2 * NE + 2 * e] : ei[NE + e];
    atomicAdd(&deg[d], 1);
}

// ---------------- multi-block scan (3 tiny kernels, was 150us single-block) ----
__global__ __launch_bounds__(256) void k_blocksum(const int* __restrict__ deg,
                                                  int* __restrict__ bsum) {
    __shared__ int s[256];
    int i = blockIdx.x * 256 + threadIdx.x;
    s[threadIdx.x] = (i < NN) ? deg[i] : 0;
    __syncthreads();
    for (int off = 128; off > 0; off >>= 1) {
        if (threadIdx.x < off) s[threadIdx.x] += s[threadIdx.x + off];
        __syncthreads();
    }
    if (threadIdx.x == 0) bsum[blockIdx.x] = s[0];
}

__global__ __launch_bounds__(256) void k_scanb(const int* __restrict__ bsum,
                                               int* __restrict__ boff) {
    __shared__ int s[256];
    int t = threadIdx.x;
    s[t] = (t < NB) ? bsum[t] : 0;
    __syncthreads();
    for (int off = 1; off < 256; off <<= 1) {
        int v = s[t];
        int a = (t >= off) ? s[t - off] : 0;
        __syncthreads();
        s[t] = v + a;
        __syncthreads();
    }
    if (t < NB) boff[t] = (t == 0) ? 0 : s[t - 1];
}

__global__ __launch_bounds__(256) void k_writeptr(const int* __restrict__ deg,
                                                  const int* __restrict__ boff,
                                                  int* __restrict__ row_ptr,
                                                  int* __restrict__ cursor,
                                                  float* __restrict__ rinv) {
    __shared__ int s[256];
    int b = blockIdx.x, t = threadIdx.x;
    int i = b * 256 + t;
    int d = (i < NN) ? deg[i] : 0;
    s[t] = d;
    __syncthreads();
    for (int off = 1; off < 256; off <<= 1) {
        int v = s[t];
        int a = (t >= off) ? s[t - off] : 0;
        __syncthreads();
        s[t] = v + a;
        __syncthreads();
    }
    if (i < NN) {
        int pos = boff[b] + s[t] - d;  // exclusive prefix
        row_ptr[i] = pos;
        cursor[i] = pos;
        rinv[i] = 1.0f / (float)max(d, 1);
    }
    if (b == 0 && t == 0) row_ptr[NN] = NE;  // every edge has dst in [0,NN)
}

__global__ void k_fill(const int* __restrict__ ei, const int* __restrict__ flag,
                       int* __restrict__ cursor, int* __restrict__ col) {
    int e = blockIdx.x * 256 + threadIdx.x;
    if (e >= NE) return;
    int is64 = *flag;
    int sv = is64 ? ei[2 * e] : ei[e];
    int dv = is64 ? ei[2 * NE + 2 * e] : ei[NE + e];
    int p = atomicAdd(&cursor[dv], 1);
    col[p] = sv;
}

// ---------------- mean aggregation: 32 lanes (float4) per node ----------------
__global__ __launch_bounds__(256) void k_aggregate(const float* __restrict__ h,
                                                   const int* __restrict__ row_ptr,
                                                   const int* __restrict__ col,
                                                   const float* __restrict__ rinv,
                                                   float* __restrict__ mean) {
    int node = blockIdx.x * 8 + (threadIdx.x >> 5);
    if (node >= NN) return;
    int lane = threadIdx.x & 31;
    int beg = row_ptr[node], end = row_ptr[node + 1];
    const float4* hp = (const float4*)h;
    float4 acc = make_float4(0.f, 0.f, 0.f, 0.f);
    int e = beg;
    // 4-deep unroll: four 512B row gathers in flight per 32-lane group
    for (; e + 3 < end; e += 4) {
        int s0 = col[e], s1 = col[e + 1], s2 = col[e + 2], s3 = col[e + 3];
        float4 v0 = hp[(size_t)s0 * 32 + lane];
        float4 v1 = hp[(size_t)s1 * 32 + lane];
        float4 v2 = hp[(size_t)s2 * 32 + lane];
        float4 v3 = hp[(size_t)s3 * 32 + lane];
        acc.x += v0.x + v1.x + v2.x + v3.x;
        acc.y += v0.y + v1.y + v2.y + v3.y;
        acc.z += v0.z + v1.z + v2.z + v3.z;
        acc.w += v0.w + v1.w + v2.w + v3.w;
    }
    for (; e < end; e++) {
        int s0 = col[e];
        float4 v0 = hp[(size_t)s0 * 32 + lane];
        acc.x += v0.x; acc.y += v0.y; acc.z += v0.z; acc.w += v0.w;
    }
    float r = rinv[node];
    acc.x *= r; acc.y *= r; acc.z *= r; acc.w *= r;
    ((float4*)mean)[(size_t)node * 32 + lane] = acc;
}

// ---------------- fused GEMM: out = mean@Wl^T + h@Wr^T + b (+ReLU) ----------------
#define TM 128
#define TKc 32
#define LDA 132
#define LDB 132

__global__ __launch_bounds__(256) void k_gemm(const float* __restrict__ Am,
                                              const float* __restrict__ Ah,
                                              const float* __restrict__ Wlp,
                                              const float* __restrict__ Wrp,
                                              const float* __restrict__ bias,
                                              float* __restrict__ outp, int relu) {
    __shared__ float As[TKc * LDA];
    __shared__ float Bs[TKc * LDB];
    const int t = threadIdx.x;
    const int nb0 = blockIdx.x * TM;
    const int n0 = (t >> 4) * 8;
    const int o0 = (t & 15) * 8;

    float acc[8][8];
#pragma unroll
    for (int i = 0; i < 8; i++)
#pragma unroll
        for (int j = 0; j < 8; j++) acc[i][j] = 0.f;

    for (int kc = 0; kc < 256; kc += TKc) {
        const float* Asrc = (kc < 128) ? Am : Ah;
        const float* Wsrc = (kc < 128) ? Wlp : Wrp;
        const int ks = kc & 127;
#pragma unroll
        for (int it = 0; it < 4; it++) {
            int lin = t + it * 256;   // 0..1023
            int row = lin >> 3;       // 0..127
            int kq = lin & 7;
            int kk = kq * 4;
            int gn = nb0 + row;
            float4 v = make_float4(0.f, 0.f, 0.f, 0.f);
            if (gn < NN) v = *(const float4*)(Asrc + (size_t)gn * 128 + ks + kk);
            As[(kk + 0) * LDA + row] = v.x;
            As[(kk + 1) * LDA + row] = v.y;
            As[(kk + 2) * LDA + row] = v.z;
            As[(kk + 3) * LDA + row] = v.w;
            float4 w = *(const float4*)(Wsrc + (size_t)row * 128 + ks + kk);
            Bs[(kk + 0) * LDB + row] = w.x;
            Bs[(kk + 1) * LDB + row] = w.y;
            Bs[(kk + 2) * LDB + row] = w.z;
            Bs[(kk + 3) * LDB + row] = w.w;
        }
        __syncthreads();
#pragma unroll 8
        for (int k = 0; k < TKc; k++) {
            float4 a0 = *(const float4*)&As[k * LDA + n0];
            float4 a1 = *(const float4*)&As[k * LDA + n0 + 4];
            float4 b0 = *(const float4*)&Bs[k * LDB + o0];
            float4 b1 = *(const float4*)&Bs[k * LDB + o0 + 4];
            float a[8] = {a0.x, a0.y, a0.z, a0.w, a1.x, a1.y, a1.z, a1.w};
            float b[8] = {b0.x, b0.y, b0.z, b0.w, b1.x, b1.y, b1.z, b1.w};
#pragma unroll
            for (int i = 0; i < 8; i++)
#pragma unroll
                for (int j = 0; j < 8; j++) acc[i][j] = fmaf(a[i], b[j], acc[i][j]);
        }
        __syncthreads();
    }

    float4 bv0 = *(const float4*)&bias[o0];
    float4 bv1 = *(const float4*)&bias[o0 + 4];
    float bb[8] = {bv0.x, bv0.y, bv0.z, bv0.w, bv1.x, bv1.y, bv1.z, bv1.w};
#pragma unroll
    for (int i = 0; i < 8; i++) {
        int gn = nb0 + n0 + i;
        if (gn < NN) {
            float4 r0, r1;
            r0.x = acc[i][0] + bb[0]; r0.y = acc[i][1] + bb[1];
            r0.z = acc[i][2] + bb[2]; r0.w = acc[i][3] + bb[3];
            r1.x = acc[i][4] + bb[4]; r1.y = acc[i][5] + bb[5];
            r1.z = acc[i][6] + bb[6]; r1.w = acc[i][7] + bb[7];
            if (relu) {
                r0.x = fmaxf(r0.x, 0.f); r0.y = fmaxf(r0.y, 0.f);
                r0.z = fmaxf(r0.z, 0.f); r0.w = fmaxf(r0.w, 0.f);
                r1.x = fmaxf(r1.x, 0.f); r1.y = fmaxf(r1.y, 0.f);
                r1.z = fmaxf(r1.z, 0.f); r1.w = fmaxf(r1.w, 0.f);
            }
            *(float4*)(outp + (size_t)gn * 128 + o0) = r0;
            *(float4*)(outp + (size_t)gn * 128 + o0 + 4) = r1;
        }
    }
}

extern "C" void kernel_launch(void* const* d_in, const int* in_sizes, int n_in,
                              void* d_out, int out_size, void* d_ws, size_t ws_size,
                              hipStream_t stream) {
    const float* x = (const float*)d_in[0];
    const int* ei = (const int*)d_in[1];
    const float* Wl[4] = {(const float*)d_in[2], (const float*)d_in[5],
                          (const float*)d_in[8], (const float*)d_in[11]};
    const float* bl[4] = {(const float*)d_in[3], (const float*)d_in[6],
                          (const float*)d_in[9], (const float*)d_in[12]};
    const float* Wr[4] = {(const float*)d_in[4], (const float*)d_in[7],
                          (const float*)d_in[10], (const float*)d_in[13]};
    float* out = (float*)d_out;

    char* p = (char*)d_ws;
    auto take = [&](size_t bytes) -> char* {
        char* r = p;
        p += (bytes + 255) & ~(size_t)255;
        return r;
    };
    int* flag = (int*)take(4);
    int* deg = (int*)take(NN * 4);
    int* row_ptr = (int*)take((NN + 1) * 4);
    int* cursor = (int*)take(NN * 4);
    float* rinv = (float*)take(NN * 4);
    int* col = (int*)take(NE * 4);
    int* bsum = (int*)take(NB * 4);
    int* boff = (int*)take(NB * 4);
    float* bufA = (float*)take((size_t)NN * 128 * 4);
    float* bufB = (float*)take((size_t)NN * 128 * 4);
    float* mbuf = (float*)take((size_t)NN * 128 * 4);

    hipMemsetAsync(deg, 0, NN * 4, stream);
    k_detect<<<1, 64, 0, stream>>>(ei, flag);
    k_count<<<(NE + 255) / 256, 256, 0, stream>>>(ei, flag, deg);
    k_blocksum<<<NB, 256, 0, stream>>>(deg, bsum);
    k_scanb<<<1, 256, 0, stream>>>(bsum, boff);
    k_writeptr<<<NB, 256, 0, stream>>>(deg, boff, row_ptr, cursor, rinv);
    k_fill<<<(NE + 255) / 256, 256, 0, stream>>>(ei, flag, cursor, col);

    const float* h = x;
    float* outs[4] = {bufA, bufB, bufA, out};
    for (int l = 0; l < 4; l++) {
        k_aggregate<<<(NN + 7) / 8, 256, 0, stream>>>(h, row_ptr, col, rinv, mbuf);
        k_gemm<<<(NN + TM - 1) / TM, 256, 0, stream>>>(mbuf, h, Wl[l], Wr[l], bl[l],
                                                       outs[l], l == 0 ? 1 : 0);
        h = outs[l];
    }
}

// Round 4
// 457.838 us; speedup vs baseline: 1.6911x; 1.3673x over previous
//
#include <hip/hip_runtime.h>
#include <stdint.h>

#define NN 50000
#define NE 800000
#define NB 196   // ceil(NN/256)

typedef short short8 __attribute__((ext_vector_type(8)));
typedef float f32x4 __attribute__((ext_vector_type(4)));
typedef unsigned int uint;
typedef unsigned short ushort;

__device__ __forceinline__ uint rne_bf16(float f) {
    uint x = __float_as_uint(f);
    return (x + 0x7FFFu + ((x >> 16) & 1u)) >> 16;  // round-to-nearest-even
}
__device__ __forceinline__ float bf_lo(uint d) { return __uint_as_float(d << 16); }
__device__ __forceinline__ float bf_hi(uint d) { return __uint_as_float(d & 0xFFFF0000u); }

// ---------------- int64-vs-int32 edge_index autodetect ----------------
__global__ void k_detect(const int* __restrict__ ei, int* __restrict__ flag) {
    if (threadIdx.x == 0 && blockIdx.x == 0) {
        int z = 0;
        for (int i = 0; i < 16; i++) z += (ei[2 * i + 1] == 0) ? 1 : 0;
        *flag = (z == 16) ? 1 : 0;
    }
}

__global__ void k_count(const int* __restrict__ ei, const int* __restrict__ flag,
                        int* __restrict__ deg) {
    int e = blockIdx.x * 256 + threadIdx.x;
    if (e >= NE) return;
    int is64 = *flag;
    int d = is64 ? ei[2 * NE + 2 * e] : ei[NE + e];
    atomicAdd(&deg[d], 1);
}

// ---------------- multi-block scan ----------------
__global__ __launch_bounds__(256) void k_blocksum(const int* __restrict__ deg,
                                                  int* __restrict__ bsum) {
    __shared__ int s[256];
    int i = blockIdx.x * 256 + threadIdx.x;
    s[threadIdx.x] = (i < NN) ? deg[i] : 0;
    __syncthreads();
    for (int off = 128; off > 0; off >>= 1) {
        if (threadIdx.x < off) s[threadIdx.x] += s[threadIdx.x + off];
        __syncthreads();
    }
    if (threadIdx.x == 0) bsum[blockIdx.x] = s[0];
}

__global__ __launch_bounds__(256) void k_scanb(const int* __restrict__ bsum,
                                               int* __restrict__ boff) {
    __shared__ int s[256];
    int t = threadIdx.x;
    s[t] = (t < NB) ? bsum[t] : 0;
    __syncthreads();
    for (int off = 1; off < 256; off <<= 1) {
        int v = s[t];
        int a = (t >= off) ? s[t - off] : 0;
        __syncthreads();
        s[t] = v + a;
        __syncthreads();
    }
    if (t < NB) boff[t] = (t == 0) ? 0 : s[t - 1];
}

__global__ __launch_bounds__(256) void k_writeptr(const int* __restrict__ deg,
                                                  const int* __restrict__ boff,
                                                  int* __restrict__ row_ptr,
                                                  int* __restrict__ cursor,
                                                  float* __restrict__ rinv) {
    __shared__ int s[256];
    int b = blockIdx.x, t = threadIdx.x;
    int i = b * 256 + t;
    int d = (i < NN) ? deg[i] : 0;
    s[t] = d;
    __syncthreads();
    for (int off = 1; off < 256; off <<= 1) {
        int v = s[t];
        int a = (t >= off) ? s[t - off] : 0;
        __syncthreads();
        s[t] = v + a;
        __syncthreads();
    }
    if (i < NN) {
        int pos = boff[b] + s[t] - d;
        row_ptr[i] = pos;
        cursor[i] = pos;
        rinv[i] = 1.0f / (float)max(d, 1);
    }
    if (b == 0 && t == 0) row_ptr[NN] = NE;
}

__global__ void k_fill(const int* __restrict__ ei, const int* __restrict__ flag,
                       int* __restrict__ cursor, int* __restrict__ col) {
    int e = blockIdx.x * 256 + threadIdx.x;
    if (e >= NE) return;
    int is64 = *flag;
    int sv = is64 ? ei[2 * e] : ei[e];
    int dv = is64 ? ei[2 * NE + 2 * e] : ei[NE + e];
    int p = atomicAdd(&cursor[dv], 1);
    col[p] = sv;
}

// ---------------- one-time casts to bf16 ----------------
__global__ __launch_bounds__(256) void k_cast_x(const float* __restrict__ x,
                                                ushort* __restrict__ xbf) {
    int i = blockIdx.x * 256 + threadIdx.x;  // exactly 1.6M threads
    float4 v = ((const float4*)x)[i];
    uint2 o;
    o.x = rne_bf16(v.x) | (rne_bf16(v.y) << 16);
    o.y = rne_bf16(v.z) | (rne_bf16(v.w) << 16);
    ((uint2*)xbf)[i] = o;
}

struct Ptrs8 { const float* p[8]; };
__global__ __launch_bounds__(256) void k_cvtW(Ptrs8 ps, ushort* __restrict__ wbf) {
    int idx = blockIdx.x * 256 + threadIdx.x;  // 0..131071
    int m = idx >> 14;
    int off = idx & 16383;
    wbf[idx] = (ushort)rne_bf16(ps.p[m][off]);
}

// ---------------- mean aggregation: 16 lanes x 16B per node (bf16 rows) -------
__global__ __launch_bounds__(256) void k_agg_bf(const ushort* __restrict__ h,
                                                const int* __restrict__ row_ptr,
                                                const int* __restrict__ col,
                                                const float* __restrict__ rinv,
                                                ushort* __restrict__ mean) {
    int node = blockIdx.x * 16 + (threadIdx.x >> 4);
    if (node >= NN) return;
    int lane = threadIdx.x & 15;
    int beg = row_ptr[node], end = row_ptr[node + 1];
    const uint4* hp = (const uint4*)h;  // row = 16 uint4 (128 bf16)
    float acc[8] = {0.f, 0.f, 0.f, 0.f, 0.f, 0.f, 0.f, 0.f};
    auto addv = [&](uint4 v) {
        acc[0] += bf_lo(v.x); acc[1] += bf_hi(v.x);
        acc[2] += bf_lo(v.y); acc[3] += bf_hi(v.y);
        acc[4] += bf_lo(v.z); acc[5] += bf_hi(v.z);
        acc[6] += bf_lo(v.w); acc[7] += bf_hi(v.w);
    };
    int e = beg;
    for (; e + 3 < end; e += 4) {  // 4 row-gathers in flight
        int s0 = col[e], s1 = col[e + 1], s2 = col[e + 2], s3 = col[e + 3];
        uint4 v0 = hp[(size_t)s0 * 16 + lane];
        uint4 v1 = hp[(size_t)s1 * 16 + lane];
        uint4 v2 = hp[(size_t)s2 * 16 + lane];
        uint4 v3 = hp[(size_t)s3 * 16 + lane];
        addv(v0); addv(v1); addv(v2); addv(v3);
    }
    for (; e < end; e++) {
        uint4 v = hp[(size_t)col[e] * 16 + lane];
        addv(v);
    }
    float r = rinv[node];
    uint4 o;
    o.x = rne_bf16(acc[0] * r) | (rne_bf16(acc[1] * r) << 16);
    o.y = rne_bf16(acc[2] * r) | (rne_bf16(acc[3] * r) << 16);
    o.z = rne_bf16(acc[4] * r) | (rne_bf16(acc[5] * r) << 16);
    o.w = rne_bf16(acc[6] * r) | (rne_bf16(acc[7] * r) << 16);
    ((uint4*)mean)[(size_t)node * 16 + lane] = o;
}

// ---------------- MFMA GEMM: out = mean@Wl^T + h@Wr^T + b (+ReLU) -------------
// LDS-free: A and B fragments are direct 16B global loads (both K-contiguous).
// 16x16x32 bf16 MFMA; A[m=lane&15][k=quad*8+j]; B[n=lane&15][k=quad*8+j];
// D: col=lane&15 (n), row=quad*4+reg (m). Wave = 16 rows x 128 cols; block = 4 waves.
__global__ __launch_bounds__(256) void k_gemm_mfma(
    const ushort* __restrict__ Am, const ushort* __restrict__ Ah,
    const ushort* __restrict__ Wlb, const ushort* __restrict__ Wrb,
    const float* __restrict__ bias, float* __restrict__ outf,
    ushort* __restrict__ outb, int relu) {
    const int lane = threadIdx.x & 63;
    const int wave = threadIdx.x >> 6;
    const int l15 = lane & 15;
    const int quad = lane >> 4;
    const int m0 = blockIdx.x * 64 + wave * 16;

    f32x4 acc[8];
#pragma unroll
    for (int t = 0; t < 8; t++) acc[t] = (f32x4){0.f, 0.f, 0.f, 0.f};

    int arow = m0 + l15;
    if (arow > NN - 1) arow = NN - 1;  // clamp loads; stores guarded below
    const ushort* Arm = Am + (size_t)arow * 128 + quad * 8;
    const ushort* Arh = Ah + (size_t)arow * 128 + quad * 8;
    const int wro = quad * 8;

#pragma unroll
    for (int half = 0; half < 2; half++) {
        const ushort* Ar = half ? Arh : Arm;
        const ushort* W = half ? Wrb : Wlb;
#pragma unroll
        for (int k0 = 0; k0 < 128; k0 += 32) {
            short8 a = *(const short8*)(Ar + k0);
#pragma unroll
            for (int t = 0; t < 8; t++) {
                short8 b = *(const short8*)(W + (size_t)(t * 16 + l15) * 128 + k0 + wro);
                acc[t] = __builtin_amdgcn_mfma_f32_16x16x32_bf16(a, b, acc[t], 0, 0, 0);
            }
        }
    }

    float bb[8];
#pragma unroll
    for (int t = 0; t < 8; t++) bb[t] = bias[t * 16 + l15];

#pragma unroll
    for (int r = 0; r < 4; r++) {
        int row = m0 + quad * 4 + r;
        if (row < NN) {
#pragma unroll
            for (int t = 0; t < 8; t++) {
                float v = acc[t][r] + bb[t];
                if (relu) v = fmaxf(v, 0.f);
                if (outb) outb[(size_t)row * 128 + t * 16 + l15] = (ushort)rne_bf16(v);
                else outf[(size_t)row * 128 + t * 16 + l15] = v;
            }
        }
    }
}

extern "C" void kernel_launch(void* const* d_in, const int* in_sizes, int n_in,
                              void* d_out, int out_size, void* d_ws, size_t ws_size,
                              hipStream_t stream) {
    const float* x = (const float*)d_in[0];
    const int* ei = (const int*)d_in[1];
    const float* Wl[4] = {(const float*)d_in[2], (const float*)d_in[5],
                          (const float*)d_in[8], (const float*)d_in[11]};
    const float* bl[4] = {(const float*)d_in[3], (const float*)d_in[6],
                          (const float*)d_in[9], (const float*)d_in[12]};
    const float* Wr[4] = {(const float*)d_in[4], (const float*)d_in[7],
                          (const float*)d_in[10], (const float*)d_in[13]};
    float* out = (float*)d_out;

    char* p = (char*)d_ws;
    auto take = [&](size_t bytes) -> char* {
        char* r = p;
        p += (bytes + 255) & ~(size_t)255;
        return r;
    };
    int* flag = (int*)take(4);
    int* deg = (int*)take(NN * 4);
    int* row_ptr = (int*)take((NN + 1) * 4);
    int* cursor = (int*)take(NN * 4);
    float* rinv = (float*)take(NN * 4);
    int* col = (int*)take(NE * 4);
    int* bsum = (int*)take(NB * 4);
    int* boff = (int*)take(NB * 4);
    ushort* xbf = (ushort*)take((size_t)NN * 128 * 2);
    ushort* h1 = (ushort*)take((size_t)NN * 128 * 2);
    ushort* h2 = (ushort*)take((size_t)NN * 128 * 2);
    ushort* meanbf = (ushort*)take((size_t)NN * 128 * 2);
    ushort* wbf = (ushort*)take(8 * 16384 * 2);

    // CSR build (once; reused by all layers)
    hipMemsetAsync(deg, 0, NN * 4, stream);
    k_detect<<<1, 64, 0, stream>>>(ei, flag);
    k_count<<<(NE + 255) / 256, 256, 0, stream>>>(ei, flag, deg);
    k_blocksum<<<NB, 256, 0, stream>>>(deg, bsum);
    k_scanb<<<1, 256, 0, stream>>>(bsum, boff);
    k_writeptr<<<NB, 256, 0, stream>>>(deg, boff, row_ptr, cursor, rinv);
    k_fill<<<(NE + 255) / 256, 256, 0, stream>>>(ei, flag, cursor, col);

    // one-time bf16 casts
    k_cast_x<<<(NN * 128 / 4) / 256, 256, 0, stream>>>(x, xbf);
    Ptrs8 ps;
    ps.p[0] = Wl[0]; ps.p[1] = Wr[0]; ps.p[2] = Wl[1]; ps.p[3] = Wr[1];
    ps.p[4] = Wl[2]; ps.p[5] = Wr[2]; ps.p[6] = Wl[3]; ps.p[7] = Wr[3];
    k_cvtW<<<512, 256, 0, stream>>>(ps, wbf);

    const ushort* h = xbf;
    ushort* houts[4] = {h1, h2, h1, nullptr};  // final layer -> fp32 d_out
    for (int l = 0; l < 4; l++) {
        k_agg_bf<<<(NN + 15) / 16, 256, 0, stream>>>(h, row_ptr, col, rinv, meanbf);
        k_gemm_mfma<<<(NN + 63) / 64, 256, 0, stream>>>(
            meanbf, h, wbf + (size_t)(2 * l) * 16384, wbf + (size_t)(2 * l + 1) * 16384,
            bl[l], out, houts[l], l == 0 ? 1 : 0);
        h = houts[l];
    }
}

// Round 5
// 439.415 us; speedup vs baseline: 1.7620x; 1.0419x over previous
//
#include <hip/hip_runtime.h>
#include <stdint.h>

#define NN 50000
#define NE 800000
#define NB 196   // ceil(NN/256)

typedef short short8 __attribute__((ext_vector_type(8)));
typedef float f32x4 __attribute__((ext_vector_type(4)));
typedef unsigned int uint;
typedef unsigned short ushort;

__device__ __forceinline__ uint rne_bf16(float f) {
    uint x = __float_as_uint(f);
    return (x + 0x7FFFu + ((x >> 16) & 1u)) >> 16;  // round-to-nearest-even
}
__device__ __forceinline__ float bf_lo(uint d) { return __uint_as_float(d << 16); }
__device__ __forceinline__ float bf_hi(uint d) { return __uint_as_float(d & 0xFFFF0000u); }

// ---------------- int64-vs-int32 edge_index autodetect (wave-parallel) --------
__global__ void k_detect(const int* __restrict__ ei, int* __restrict__ flag) {
    int l = threadIdx.x;
    int v = (l < 16) ? ei[2 * l + 1] : 0;
    unsigned long long nz = __ballot(v != 0);
    if (l == 0 && blockIdx.x == 0) *flag = (nz == 0ULL) ? 1 : 0;
}

// count degrees AND record each edge's arrival rank (atomicAdd return value).
// rank makes k_fill deterministic -> no atomics there.
__global__ void k_count(const int* __restrict__ ei, const int* __restrict__ flag,
                        int* __restrict__ deg, ushort* __restrict__ rank) {
    int e = blockIdx.x * 256 + threadIdx.x;
    if (e >= NE) return;
    int is64 = *flag;
    int d = is64 ? ei[2 * NE + 2 * e] : ei[NE + e];
    int rk = atomicAdd(&deg[d], 1);
    rank[e] = (ushort)rk;
}

// ---------------- multi-block scan ----------------
__global__ __launch_bounds__(256) void k_blocksum(const int* __restrict__ deg,
                                                  int* __restrict__ bsum) {
    __shared__ int s[256];
    int i = blockIdx.x * 256 + threadIdx.x;
    s[threadIdx.x] = (i < NN) ? deg[i] : 0;
    __syncthreads();
    for (int off = 128; off > 0; off >>= 1) {
        if (threadIdx.x < off) s[threadIdx.x] += s[threadIdx.x + off];
        __syncthreads();
    }
    if (threadIdx.x == 0) bsum[blockIdx.x] = s[0];
}

__global__ __launch_bounds__(256) void k_scanb(const int* __restrict__ bsum,
                                               int* __restrict__ boff) {
    __shared__ int s[256];
    int t = threadIdx.x;
    s[t] = (t < NB) ? bsum[t] : 0;
    __syncthreads();
    for (int off = 1; off < 256; off <<= 1) {
        int v = s[t];
        int a = (t >= off) ? s[t - off] : 0;
        __syncthreads();
        s[t] = v + a;
        __syncthreads();
    }
    if (t < NB) boff[t] = (t == 0) ? 0 : s[t - 1];
}

__global__ __launch_bounds__(256) void k_writeptr(const int* __restrict__ deg,
                                                  const int* __restrict__ boff,
                                                  int* __restrict__ row_ptr,
                                                  float* __restrict__ rinv) {
    __shared__ int s[256];
    int b = blockIdx.x, t = threadIdx.x;
    int i = b * 256 + t;
    int d = (i < NN) ? deg[i] : 0;
    s[t] = d;
    __syncthreads();
    for (int off = 1; off < 256; off <<= 1) {
        int v = s[t];
        int a = (t >= off) ? s[t - off] : 0;
        __syncthreads();
        s[t] = v + a;
        __syncthreads();
    }
    if (i < NN) {
        int pos = boff[b] + s[t] - d;
        row_ptr[i] = pos;
        rinv[i] = 1.0f / (float)max(d, 1);
    }
    if (b == 0 && t == 0) row_ptr[NN] = NE;
}

// deterministic fill: p = row_ptr[dst] + rank[e]; no atomics.
__global__ void k_fill(const int* __restrict__ ei, const int* __restrict__ flag,
                       const int* __restrict__ row_ptr,
                       const ushort* __restrict__ rank, ushort* __restrict__ col) {
    int e = blockIdx.x * 256 + threadIdx.x;
    if (e >= NE) return;
    int is64 = *flag;
    int sv = is64 ? ei[2 * e] : ei[e];
    int dv = is64 ? ei[2 * NE + 2 * e] : ei[NE + e];
    int p = row_ptr[dv] + (int)rank[e];
    col[p] = (ushort)sv;  // src < 50000 < 65536
}

// ---------------- one-time casts to bf16 ----------------
__global__ __launch_bounds__(256) void k_cast_x(const float* __restrict__ x,
                                                ushort* __restrict__ xbf) {
    int i = blockIdx.x * 256 + threadIdx.x;  // 1.6M threads, 4 floats each
    float4 v = ((const float4*)x)[i];
    uint2 o;
    o.x = rne_bf16(v.x) | (rne_bf16(v.y) << 16);
    o.y = rne_bf16(v.z) | (rne_bf16(v.w) << 16);
    ((uint2*)xbf)[i] = o;
}

struct Ptrs8 { const float* p[8]; };
__global__ __launch_bounds__(256) void k_cvtW(Ptrs8 ps, ushort* __restrict__ wbf) {
    int idx = blockIdx.x * 256 + threadIdx.x;  // 0..131071
    int m = idx >> 14;
    int off = idx & 16383;
    wbf[idx] = (ushort)rne_bf16(ps.p[m][off]);
}

// ---------------- fused layer: aggregate (LDS) + MFMA GEMM --------------------
// Block = 256 threads = 4 waves = 64 nodes. Phase 1: each 16-lane group
// aggregates 4 nodes over their contiguous CSR edge range (col preloaded 16 at
// a time, shfl-broadcast, 8 gathers in flight, mask-FMA into the right node's
// acc). Mean rows land in LDS (pitch 136 ushort: +16B pad, 16B-aligned).
// Phase 2: 16x16x32 bf16 MFMA; A(mean) from LDS, A(h) + B(W) from global.
__global__ __launch_bounds__(256) void k_layer(
    const ushort* __restrict__ h, const int* __restrict__ row_ptr,
    const ushort* __restrict__ col, const float* __restrict__ rinv,
    const ushort* __restrict__ Wlb, const ushort* __restrict__ Wrb,
    const float* __restrict__ bias, float* __restrict__ outf,
    ushort* __restrict__ outb, int relu) {
    __shared__ __align__(16) ushort Asm[64][136];
    const int tid = threadIdx.x;
    const int wave = tid >> 6;
    const int lane = tid & 63;
    const int l16 = lane & 15;
    const int g = lane >> 4;  // group within wave == MFMA quad
    const int blk0 = blockIdx.x * 64;
    const int w0 = wave * 16;

    const uint4* hp = (const uint4*)h;

    // ---- phase 1: aggregation ----
    {
        int nbase = blk0 + w0 + g * 4;  // group's first node
        int rp[5];
#pragma unroll
        for (int k = 0; k < 5; k++) rp[k] = row_ptr[min(nbase + k, NN)];
        float acc[4][8];
#pragma unroll
        for (int k = 0; k < 4; k++)
#pragma unroll
            for (int d = 0; d < 8; d++) acc[k][d] = 0.f;

        const int T = rp[4] - rp[0];
        for (int c0 = 0; c0 < T; c0 += 16) {
            int ci = rp[0] + c0 + l16;
            int cs = (c0 + l16 < T) ? (int)col[ci] : 0;
#pragma unroll
            for (int jb = 0; jb < 16; jb += 8) {
                if (c0 + jb < T) {  // uniform per group: skip fully-dead batch
#pragma unroll
                    for (int j = 0; j < 8; j++) {
                        int e = rp[0] + c0 + jb + j;
                        int s = __shfl(cs, (g << 4) | (jb + j));
                        uint4 v = hp[(size_t)s * 16 + l16];
                        float mm[4];
                        mm[0] = (e < rp[1]) ? 1.f : 0.f;
                        mm[1] = (e >= rp[1] && e < rp[2]) ? 1.f : 0.f;
                        mm[2] = (e >= rp[2] && e < rp[3]) ? 1.f : 0.f;
                        mm[3] = (e >= rp[3] && e < rp[4]) ? 1.f : 0.f;
                        float fv[8];
                        fv[0] = bf_lo(v.x); fv[1] = bf_hi(v.x);
                        fv[2] = bf_lo(v.y); fv[3] = bf_hi(v.y);
                        fv[4] = bf_lo(v.z); fv[5] = bf_hi(v.z);
                        fv[6] = bf_lo(v.w); fv[7] = bf_hi(v.w);
#pragma unroll
                        for (int k = 0; k < 4; k++)
#pragma unroll
                            for (int d = 0; d < 8; d++)
                                acc[k][d] = fmaf(mm[k], fv[d], acc[k][d]);
                    }
                }
            }
        }
#pragma unroll
        for (int k = 0; k < 4; k++) {
            float r = rinv[min(nbase + k, NN - 1)];
            uint4 o;
            o.x = rne_bf16(acc[k][0] * r) | (rne_bf16(acc[k][1] * r) << 16);
            o.y = rne_bf16(acc[k][2] * r) | (rne_bf16(acc[k][3] * r) << 16);
            o.z = rne_bf16(acc[k][4] * r) | (rne_bf16(acc[k][5] * r) << 16);
            o.w = rne_bf16(acc[k][6] * r) | (rne_bf16(acc[k][7] * r) << 16);
            *(uint4*)&Asm[w0 + g * 4 + k][l16 * 8] = o;
        }
    }
    __syncthreads();

    // ---- phase 2: MFMA GEMM out = mean@Wl^T + h@Wr^T + b ----
    f32x4 dacc[8];
#pragma unroll
    for (int t = 0; t < 8; t++) dacc[t] = (f32x4){0.f, 0.f, 0.f, 0.f};

    const int wro = g * 8;  // quad's k-slice
    // half 0: A = mean (LDS)
#pragma unroll
    for (int k0 = 0; k0 < 128; k0 += 32) {
        short8 a = *(const short8*)&Asm[w0 + l16][k0 + wro];
#pragma unroll
        for (int t = 0; t < 8; t++) {
            short8 b = *(const short8*)(Wlb + (size_t)(t * 16 + l16) * 128 + k0 + wro);
            dacc[t] = __builtin_amdgcn_mfma_f32_16x16x32_bf16(a, b, dacc[t], 0, 0, 0);
        }
    }
    // half 1: A = h (global)
    int arow = min(blk0 + w0 + l16, NN - 1);
    const ushort* Arh = h + (size_t)arow * 128 + wro;
#pragma unroll
    for (int k0 = 0; k0 < 128; k0 += 32) {
        short8 a = *(const short8*)(Arh + k0);
#pragma unroll
        for (int t = 0; t < 8; t++) {
            short8 b = *(const short8*)(Wrb + (size_t)(t * 16 + l16) * 128 + k0 + wro);
            dacc[t] = __builtin_amdgcn_mfma_f32_16x16x32_bf16(a, b, dacc[t], 0, 0, 0);
        }
    }

    float bb[8];
#pragma unroll
    for (int t = 0; t < 8; t++) bb[t] = bias[t * 16 + l16];

    const int m0 = blk0 + w0;
#pragma unroll
    for (int r = 0; r < 4; r++) {
        int row = m0 + g * 4 + r;  // C/D: row = quad*4 + reg
        if (row < NN) {
#pragma unroll
            for (int t = 0; t < 8; t++) {
                float v = dacc[t][r] + bb[t];
                if (relu) v = fmaxf(v, 0.f);
                if (outb) outb[(size_t)row * 128 + t * 16 + l16] = (ushort)rne_bf16(v);
                else outf[(size_t)row * 128 + t * 16 + l16] = v;
            }
        }
    }
}

extern "C" void kernel_launch(void* const* d_in, const int* in_sizes, int n_in,
                              void* d_out, int out_size, void* d_ws, size_t ws_size,
                              hipStream_t stream) {
    const float* x = (const float*)d_in[0];
    const int* ei = (const int*)d_in[1];
    const float* Wl[4] = {(const float*)d_in[2], (const float*)d_in[5],
                          (const float*)d_in[8], (const float*)d_in[11]};
    const float* bl[4] = {(const float*)d_in[3], (const float*)d_in[6],
                          (const float*)d_in[9], (const float*)d_in[12]};
    const float* Wr[4] = {(const float*)d_in[4], (const float*)d_in[7],
                          (const float*)d_in[10], (const float*)d_in[13]};
    float* out = (float*)d_out;

    char* p = (char*)d_ws;
    auto take = [&](size_t bytes) -> char* {
        char* r = p;
        p += (bytes + 255) & ~(size_t)255;
        return r;
    };
    int* flag = (int*)take(4);
    int* deg = (int*)take(NN * 4);
    int* row_ptr = (int*)take((NN + 1) * 4);
    float* rinv = (float*)take(NN * 4);
    int* bsum = (int*)take(NB * 4);
    int* boff = (int*)take(NB * 4);
    ushort* rank = (ushort*)take((size_t)NE * 2);
    ushort* col = (ushort*)take((size_t)NE * 2);
    ushort* xbf = (ushort*)take((size_t)NN * 128 * 2);
    ushort* h1 = (ushort*)take((size_t)NN * 128 * 2);
    ushort* h2 = (ushort*)take((size_t)NN * 128 * 2);
    ushort* wbf = (ushort*)take(8 * 16384 * 2);

    // CSR build (once; reused by all 4 layers)
    hipMemsetAsync(deg, 0, NN * 4, stream);
    k_detect<<<1, 64, 0, stream>>>(ei, flag);
    k_count<<<(NE + 255) / 256, 256, 0, stream>>>(ei, flag, deg, rank);
    k_blocksum<<<NB, 256, 0, stream>>>(deg, bsum);
    k_scanb<<<1, 256, 0, stream>>>(bsum, boff);
    k_writeptr<<<NB, 256, 0, stream>>>(deg, boff, row_ptr, rinv);
    k_fill<<<(NE + 255) / 256, 256, 0, stream>>>(ei, flag, row_ptr, rank, col);

    // one-time bf16 casts
    k_cast_x<<<(NN * 128 / 4) / 256, 256, 0, stream>>>(x, xbf);
    Ptrs8 ps;
    ps.p[0] = Wl[0]; ps.p[1] = Wr[0]; ps.p[2] = Wl[1]; ps.p[3] = Wr[1];
    ps.p[4] = Wl[2]; ps.p[5] = Wr[2]; ps.p[6] = Wl[3]; ps.p[7] = Wr[3];
    k_cvtW<<<512, 256, 0, stream>>>(ps, wbf);

    const ushort* h = xbf;
    ushort* houts[4] = {h1, h2, h1, nullptr};  // final layer -> fp32 d_out
    for (int l = 0; l < 4; l++) {
        k_layer<<<(NN + 63) / 64, 256, 0, stream>>>(
            h, row_ptr, col, rinv, wbf + (size_t)(2 * l) * 16384,
            wbf + (size_t)(2 * l + 1) * 16384, bl[l], out, houts[l],
            l == 0 ? 1 : 0);
        h = houts[l];
    }
}